// Round 8
// baseline (256.849 us; speedup 1.0000x reference)
//
#include <hip/hip_runtime.h>
#include <math.h>

#define Bb 2
#define Qq 4096
#define Cc 256
#define Nn 6
#define Hh 64
#define Ww 96
#define HEADS 8
#define POINTS 4
#define HW (Hh*Ww)            // 6144
#define BQ (Bb*Qq)            // 8192

// workspace layout (float offsets)
#define WS_VAL   0             // bf16 val [B,N,HEADS,H,W,32] : 18,874,368 sh
#define WS_WTF   9437184       // bf16 W_val^T frag-linear : 65,536 sh
#define WS_WCHF  9469952       // bf16 Wcat^T hi frag-linear: 147,456 sh
#define WS_WCLF  9543680       // bf16 Wcat^T lo frag-linear
#define WS_WOTF  9617408       // bf16 W_out^T frag-linear : 65,536 sh
#define WS_LOCS  18874368      // f32 [B,Q,384]
#define WS_AW    22020096      // f32 [B,Q,192]
#define WS_REFF  23592960      // f32 [B,N,Q,3]
#define WS_WSUM  23740416      // bf16 [B,Q,C] : 1,048,576 fl
#define WS_HIST  24788992      // int[2048]
#define WS_BOFF  24791040      // int[2048]
#define WS_BIN   24793088      // int[8192]
#define WS_PERM  24801280      // int[8192]

typedef __attribute__((ext_vector_type(8))) short short8;
typedef __attribute__((ext_vector_type(4))) float f32x4;

__device__ __forceinline__ unsigned short f2bf(float f) {
    union { float f; unsigned u; } v; v.f = f;
    unsigned r = (v.u + 0x7fffu + ((v.u >> 16) & 1u)) >> 16;
    return (unsigned short)r;
}
__device__ __forceinline__ float bf2f(unsigned short h) { return __uint_as_float((unsigned)h << 16); }
__device__ __forceinline__ float bflo(unsigned u) { return __uint_as_float(u << 16); }
__device__ __forceinline__ float bfhi(unsigned u) { return __uint_as_float(u & 0xffff0000u); }
__device__ __forceinline__ unsigned packbf(float a, float b) {
    return (unsigned)f2bf(a) | ((unsigned)f2bf(b) << 16);
}

// ---------------------------------------------------------------------------
// Kernel PREP: blocks [0,32): fisheye ref+fov.  blocks [32,1120): weight
// casts into MFMA-fragment-linear layouts.
// ---------------------------------------------------------------------------
__global__ void prep_kernel(const float* __restrict__ qc,
                            const float* __restrict__ intr,
                            const float* __restrict__ invE,
                            float* __restrict__ reff,
                            const float* __restrict__ Wv,
                            const float* __restrict__ Wo,
                            const float* __restrict__ Wa,
                            const float* __restrict__ Wu,
                            unsigned short* __restrict__ Wtf,
                            unsigned short* __restrict__ Wchf,
                            unsigned short* __restrict__ Wclf,
                            unsigned short* __restrict__ Wotf) {
    int blk = blockIdx.x;
    int tid = threadIdx.x;
    if (blk < 32) {
        int idx = blk * 256 + tid;
        int b = idx >> 12;
        int q = idx & (Qq - 1);
        float rx = qc[idx*3+0] * 7.2f - 3.6f;
        float ry = qc[idx*3+1] * 6.0f - 3.0f;
        float rz = qc[idx*3+2] * 3.2f - 0.7f;
        for (int n = 0; n < Nn; ++n) {
            const float* E = invE + (b*Nn+n)*16;
            float camx = E[0]*rx + E[1]*ry + E[2]*rz  + E[3];
            float camy = E[4]*rx + E[5]*ry + E[6]*rz  + E[7];
            float camz = E[8]*rx + E[9]*ry + E[10]*rz + E[11];
            const float* K = intr + (b*Nn+n)*9;
            float fx = K[0], cx0 = K[2], cy0 = K[5];
            float r3d   = sqrtf(camx*camx + camy*camy + 1e-8f);
            float theta = atan2f(r3d, camz);
            float phi   = atan2f(camy, camx);
            float r_img = fx * theta;
            float u = r_img * cosf(phi) + cx0;
            float v = r_img * sinf(phi) + cy0;
            int base = ((b*Nn+n)*Qq + q)*3;
            reff[base+0] = 2.0f * u / 1279.0f - 1.0f;
            reff[base+1] = 2.0f * v / 1079.0f - 1.0f;
            reff[base+2] = (camz > 0.0f && theta < 1.372f) ? 1.0f : 0.0f;
        }
        return;
    }
    int idx = (blk - 32) * 256 + tid;     // [0, 278528)
    if (idx < 65536) {
        int s = idx & 7, l = (idx >> 3) & 63, kk = (idx >> 9) & 7, t = idx >> 12;
        int n = t*16 + (l & 15);
        int k = kk*32 + (l >> 4)*8 + s;
        Wtf[idx] = f2bf(Wv[k*256 + n]);
    } else if (idx < 212992) {
        int i2 = idx - 65536;
        int s = i2 & 7, l = (i2 >> 3) & 63, kk = (i2 >> 9) & 7, t = i2 >> 12;
        int n = t*16 + (l & 15);
        int k = kk*32 + (l >> 4)*8 + s;
        float w = (n < 384) ? Wo[k*384 + n] : Wa[k*192 + (n - 384)];
        unsigned short h = f2bf(w);
        Wchf[i2] = h;
        Wclf[i2] = f2bf(w - bf2f(h));
    } else {
        int i3 = idx - 212992;
        int s = i3 & 7, l = (i3 >> 3) & 63, kk = (i3 >> 9) & 7, t = i3 >> 12;
        int n = t*16 + (l & 15);
        int k = kk*32 + (l >> 4)*8 + s;
        Wotf[i3] = f2bf(Wu[k*256 + n]);
    }
}

// ---------------------------------------------------------------------------
// Spatial binning of queries: 16x16x8 = 2048 voxel bins -> counting sort.
// Co-located queries land in the same samp block -> L2 reuse of val granules.
// ---------------------------------------------------------------------------
__global__ void bin_kernel(const float* __restrict__ qc,
                           int* __restrict__ hist, int* __restrict__ bin) {
    int q = blockIdx.x*256 + threadIdx.x;        // 8192
    float x = qc[q*3+0], y = qc[q*3+1], z = qc[q*3+2];
    int bx = min(15, max(0, (int)(x*16.f)));
    int by = min(15, max(0, (int)(y*16.f)));
    int bz = min(7,  max(0, (int)(z*8.f)));
    int b = q >> 12;                             // keep batches separate (val planes differ)
    int bn = (((b*8 + bz)*16 + by)*16 + bx) & 2047;
    bin[q] = bn;
    atomicAdd(&hist[bn], 1);
}

__global__ void scan_kernel(const int* __restrict__ hist, int* __restrict__ boff) {
    __shared__ int psum[256];
    int t = threadIdx.x;
    int loc[8]; int s = 0;
#pragma unroll
    for (int i = 0; i < 8; ++i) { loc[i] = hist[t*8+i]; s += loc[i]; }
    psum[t] = s;
    __syncthreads();
    for (int off = 1; off < 256; off <<= 1) {
        int v = (t >= off) ? psum[t-off] : 0;
        __syncthreads();
        psum[t] += v;
        __syncthreads();
    }
    int base = (t == 0) ? 0 : psum[t-1];
#pragma unroll
    for (int i = 0; i < 8; ++i) { boff[t*8+i] = base; base += loc[i]; }
}

__global__ void scatter_kernel(const int* __restrict__ bin,
                               int* __restrict__ boff, int* __restrict__ perm) {
    int q = blockIdx.x*256 + threadIdx.x;
    int pos = atomicAdd(&boff[bin[q]], 1);
    perm[pos] = q;
}

// ---------------------------------------------------------------------------
// Kernel VP (MFMA): value projection -> val in HEAD-MAJOR layout:
// val[b,n,head,h,w,32ch].
// ---------------------------------------------------------------------------
__global__ __launch_bounds__(512, 2) void vp_mfma_kernel(const float* __restrict__ feats,
                                                         const unsigned short* __restrict__ Wtf,
                                                         const float* __restrict__ bv,
                                                         unsigned short* __restrict__ val) {
    __shared__ __align__(16) unsigned short As[64 * 272];   // 34.8 KB
    int t = threadIdx.x;
    int pix0 = blockIdx.x * 64;
    int bn = blockIdx.y;
    const float* A = feats + (size_t)bn * Cc * HW + pix0;
    int lane = t & 63, wavei = t >> 6, quad = lane >> 4, l15 = lane & 15;
    // ---- staging: pixel-quad pq = t&15, k-octet oct = t>>4 ----
    {
        int pq = t & 15;
        int oct = t >> 4;
        float va[8][4];
#pragma unroll
        for (int j = 0; j < 8; ++j)
            *(float4*)va[j] = *(const float4*)&A[(size_t)(oct*8 + j)*HW + pq*4];
#pragma unroll
        for (int e = 0; e < 4; ++e) {
            int m = pq*4 + e;
            uint4 pk;
            pk.x = packbf(va[0][e], va[1][e]);
            pk.y = packbf(va[2][e], va[3][e]);
            pk.z = packbf(va[4][e], va[5][e]);
            pk.w = packbf(va[6][e], va[7][e]);
            *(uint4*)&As[m*264 + oct*8] = pk;
        }
    }
    __syncthreads();
    // ---- compute ----
    int wm = wavei & 1;
    int wn = wavei >> 1;
    int r0 = wm*32 + l15, r1 = r0 + 16;
    const unsigned short* Wl = Wtf + (size_t)lane * 8;
#define VP_BOFF(nt, kk) ((size_t)(((wn*4 + (nt))*8 + (kk)) << 9))
    f32x4 acc[2][4];
#pragma unroll
    for (int i = 0; i < 2; ++i)
#pragma unroll
        for (int j = 0; j < 4; ++j) acc[i][j] = (f32x4){0.f, 0.f, 0.f, 0.f};
    short8 bA[4], bB[4];
#pragma unroll
    for (int nt = 0; nt < 4; ++nt) bA[nt] = *(const short8*)&Wl[VP_BOFF(nt, 0)];
#pragma unroll
    for (int kk = 0; kk < 8; kk += 2) {
        if (kk + 1 < 8) {
#pragma unroll
            for (int nt = 0; nt < 4; ++nt) bB[nt] = *(const short8*)&Wl[VP_BOFF(nt, kk+1)];
        }
        {
            short8 a0 = *(const short8*)&As[r0*264 + kk*32 + quad*8];
            short8 a1 = *(const short8*)&As[r1*264 + kk*32 + quad*8];
#pragma unroll
            for (int nt = 0; nt < 4; ++nt) {
                acc[0][nt] = __builtin_amdgcn_mfma_f32_16x16x32_bf16(a0, bA[nt], acc[0][nt], 0, 0, 0);
                acc[1][nt] = __builtin_amdgcn_mfma_f32_16x16x32_bf16(a1, bA[nt], acc[1][nt], 0, 0, 0);
            }
        }
        if (kk + 2 < 8) {
#pragma unroll
            for (int nt = 0; nt < 4; ++nt) bA[nt] = *(const short8*)&Wl[VP_BOFF(nt, kk+2)];
        }
        if (kk + 1 < 8) {
            int k1 = kk + 1;
            short8 a0 = *(const short8*)&As[r0*264 + k1*32 + quad*8];
            short8 a1 = *(const short8*)&As[r1*264 + k1*32 + quad*8];
#pragma unroll
            for (int nt = 0; nt < 4; ++nt) {
                acc[0][nt] = __builtin_amdgcn_mfma_f32_16x16x32_bf16(a0, bB[nt], acc[0][nt], 0, 0, 0);
                acc[1][nt] = __builtin_amdgcn_mfma_f32_16x16x32_bf16(a1, bB[nt], acc[1][nt], 0, 0, 0);
            }
        }
    }
    // ---- epilogue: transpose via LDS (272-stride), head-major stores ----
    __syncthreads();
#pragma unroll
    for (int nt = 0; nt < 4; ++nt) {
        int n = wn*64 + nt*16 + l15;
        float bias = bv[n];
#pragma unroll
        for (int mt = 0; mt < 2; ++mt) {
#pragma unroll
            for (int r = 0; r < 4; ++r) {
                int mm = wm*32 + mt*16 + quad*4 + r;
                As[mm*272 + n] = f2bf(acc[mt][nt][r] + bias);
            }
        }
    }
    __syncthreads();
#pragma unroll
    for (int i = 0; i < 4; ++i) {
        int flat = wavei*2048 + i*512 + lane*8;    // shorts
        int pix = flat >> 8, ch = flat & 255;
        int head = ch >> 5, c32 = ch & 31;
        *(uint4*)&val[(((size_t)bn*HEADS + head)*HW + pix0 + pix)*32 + c32] =
            *(const uint4*)&As[pix*272 + ch];
    }
}

// ---------------------------------------------------------------------------
// Kernel QP: fused query projection.
// grid.y = ty: 0,1 -> offsets tiles (hi/lo 3-pass), 2 -> attn (single pass).
// ---------------------------------------------------------------------------
__global__ __launch_bounds__(512, 4) void qp_kernel(const float* __restrict__ query,
                                                    const unsigned short* __restrict__ Wchf,
                                                    const unsigned short* __restrict__ Wclf,
                                                    const float* __restrict__ b_off,
                                                    const float* __restrict__ b_attn,
                                                    const float* __restrict__ reff,
                                                    float* __restrict__ locs,
                                                    float* __restrict__ aw) {
    __shared__ __align__(16) unsigned short Ah[32 * 256];   // 16 KB
    __shared__ __align__(16) unsigned short Al[32 * 256];   // 16 KB
    int t = threadIdx.x;
    int row0 = blockIdx.x * 32;
    int ty = blockIdx.y;
    {
        int row = t & 31;
        int c2 = t >> 5;
        const float* src = query + (size_t)(row0 + row) * 256;
#pragma unroll
        for (int cc = 0; cc < 2; ++cc) {
            int c = c2 * 2 + cc;
            float4 v0 = *(const float4*)&src[c*8 + 0];
            float4 v1 = *(const float4*)&src[c*8 + 4];
            float f[8] = {v0.x, v0.y, v0.z, v0.w, v1.x, v1.y, v1.z, v1.w};
            unsigned short h[8], l[8];
#pragma unroll
            for (int j = 0; j < 8; ++j) {
                h[j] = f2bf(f[j]);
                l[j] = f2bf(f[j] - bf2f(h[j]));
            }
            uint4 ph, pl;
            ph.x = h[0] | ((unsigned)h[1] << 16); ph.y = h[2] | ((unsigned)h[3] << 16);
            ph.z = h[4] | ((unsigned)h[5] << 16); ph.w = h[6] | ((unsigned)h[7] << 16);
            pl.x = l[0] | ((unsigned)l[1] << 16); pl.y = l[2] | ((unsigned)l[3] << 16);
            pl.z = l[4] | ((unsigned)l[5] << 16); pl.w = l[6] | ((unsigned)l[7] << 16);
            int pos = row * 256 + ((c ^ row) << 3);
            *(uint4*)&Ah[pos] = ph;
            *(uint4*)&Al[pos] = pl;
        }
    }
    __syncthreads();
    int wave = t >> 6, lane = t & 63, quad = lane >> 4, l15 = lane & 15;
    int ms = wave & 1;
    int ng = wave >> 1;
    int arow = ms*16 + l15;
    int bq = row0 >> 12;
    int tile0 = ty*12 + ng*3;
    f32x4 acc[3];
#pragma unroll
    for (int i = 0; i < 3; ++i) acc[i] = (f32x4){0.f, 0.f, 0.f, 0.f};

#define QP_FB(i, kk) (((size_t)((tile0 + (i))*8 + (kk)) << 9) + lane*8)

    if (ty < 2) {
        short8 bhA[3], blA[3], bhB[3], blB[3];
#pragma unroll
        for (int i = 0; i < 3; ++i) {
            bhA[i] = *(const short8*)&Wchf[QP_FB(i, 0)];
            blA[i] = *(const short8*)&Wclf[QP_FB(i, 0)];
        }
#pragma unroll
        for (int kk = 0; kk < 8; kk += 2) {
            if (kk + 1 < 8) {
#pragma unroll
                for (int i = 0; i < 3; ++i) {
                    bhB[i] = *(const short8*)&Wchf[QP_FB(i, kk+1)];
                    blB[i] = *(const short8*)&Wclf[QP_FB(i, kk+1)];
                }
            }
            {
                int apos = arow*256 + (((kk*4+quad) ^ arow) << 3);
                short8 a_h = *(const short8*)&Ah[apos];
                short8 a_l = *(const short8*)&Al[apos];
#pragma unroll
                for (int i = 0; i < 3; ++i) {
                    acc[i] = __builtin_amdgcn_mfma_f32_16x16x32_bf16(a_h, bhA[i], acc[i], 0, 0, 0);
                    acc[i] = __builtin_amdgcn_mfma_f32_16x16x32_bf16(a_l, bhA[i], acc[i], 0, 0, 0);
                    acc[i] = __builtin_amdgcn_mfma_f32_16x16x32_bf16(a_h, blA[i], acc[i], 0, 0, 0);
                }
            }
            if (kk + 2 < 8) {
#pragma unroll
                for (int i = 0; i < 3; ++i) {
                    bhA[i] = *(const short8*)&Wchf[QP_FB(i, kk+2)];
                    blA[i] = *(const short8*)&Wclf[QP_FB(i, kk+2)];
                }
            }
            if (kk + 1 < 8) {
                int k1 = kk + 1;
                int apos = arow*256 + (((k1*4+quad) ^ arow) << 3);
                short8 a_h = *(const short8*)&Ah[apos];
                short8 a_l = *(const short8*)&Al[apos];
#pragma unroll
                for (int i = 0; i < 3; ++i) {
                    acc[i] = __builtin_amdgcn_mfma_f32_16x16x32_bf16(a_h, bhB[i], acc[i], 0, 0, 0);
                    acc[i] = __builtin_amdgcn_mfma_f32_16x16x32_bf16(a_l, bhB[i], acc[i], 0, 0, 0);
                    acc[i] = __builtin_amdgcn_mfma_f32_16x16x32_bf16(a_h, blB[i], acc[i], 0, 0, 0);
                }
            }
        }
#pragma unroll
        for (int i = 0; i < 3; ++i) {
            int j = (tile0 + i)*16 + l15;
            int n_cam = j >> 6;
            int xy = j & 1;
            float bias = b_off[j];
#pragma unroll
            for (int r = 0; r < 4; ++r) {
                int q = row0 + ms*16 + quad*4 + r;
                int qq = q & (Qq-1);
                float refv = reff[((bq*Nn + n_cam)*Qq + qq)*3 + xy];
                locs[(size_t)q*384 + j] = refv + tanhf(acc[i][r] + bias) * 0.5f;
            }
        }
    } else {
        short8 bhA[3], bhB[3];
#pragma unroll
        for (int i = 0; i < 3; ++i) bhA[i] = *(const short8*)&Wchf[QP_FB(i, 0)];
#pragma unroll
        for (int kk = 0; kk < 8; kk += 2) {
            if (kk + 1 < 8) {
#pragma unroll
                for (int i = 0; i < 3; ++i) bhB[i] = *(const short8*)&Wchf[QP_FB(i, kk+1)];
            }
            {
                int apos = arow*256 + (((kk*4+quad) ^ arow) << 3);
                short8 a_h = *(const short8*)&Ah[apos];
#pragma unroll
                for (int i = 0; i < 3; ++i)
                    acc[i] = __builtin_amdgcn_mfma_f32_16x16x32_bf16(a_h, bhA[i], acc[i], 0, 0, 0);
            }
            if (kk + 2 < 8) {
#pragma unroll
                for (int i = 0; i < 3; ++i) bhA[i] = *(const short8*)&Wchf[QP_FB(i, kk+2)];
            }
            if (kk + 1 < 8) {
                int k1 = kk + 1;
                int apos = arow*256 + (((k1*4+quad) ^ arow) << 3);
                short8 a_h = *(const short8*)&Ah[apos];
#pragma unroll
                for (int i = 0; i < 3; ++i)
                    acc[i] = __builtin_amdgcn_mfma_f32_16x16x32_bf16(a_h, bhB[i], acc[i], 0, 0, 0);
            }
        }
#pragma unroll
        for (int i = 0; i < 3; ++i) {
            int j2 = (tile0 + i)*16 + l15 - 384;
            int n_cam = j2 >> 5;
            float bias = b_attn[j2];
#pragma unroll
            for (int r = 0; r < 4; ++r) {
                int q = row0 + ms*16 + quad*4 + r;
                int qq = q & (Qq-1);
                float fov = reff[((bq*Nn + n_cam)*Qq + qq)*3 + 2];
                float lg = (acc[i][r] + bias) * fov;
                float mx = fmaxf(lg, __shfl_xor(lg, 1));
                mx = fmaxf(mx, __shfl_xor(mx, 2));
                float e = expf(lg - mx);
                float s = e + __shfl_xor(e, 1);
                s = s + __shfl_xor(s, 2);
                aw[(size_t)q*192 + j2] = e / s;
            }
        }
    }
#undef QP_FB
}

// ---------------------------------------------------------------------------
// Kernel S: bilinear sampling (head-major bf16 val) + weighted sum -> wsum.
// Queries taken through the spatial-bin permutation for L2 locality.
// ---------------------------------------------------------------------------
__global__ __launch_bounds__(256, 4) void samp_kernel(const unsigned short* __restrict__ val,
                                                      const float* __restrict__ locs,
                                                      const float* __restrict__ aw,
                                                      const int* __restrict__ perm,
                                                      unsigned short* __restrict__ wsum) {
    __shared__ float swgt[4][4][200];
    __shared__ int   soff[4][4][200];
    int t = threadIdx.x, wv = t >> 6, lane = t & 63;
    int q = perm[blockIdx.x * 4 + wv];
    int b = q >> 12;
#pragma unroll
    for (int j = 0; j < 3; ++j) {
        int s = lane + 64*j;
        float2 xy = *(const float2*)&locs[(size_t)q*384 + 2*s];
        float w = aw[(size_t)q*192 + s];
        float gx = (xy.x + 1.0f)*48.0f - 0.5f;
        float gy = (xy.y + 1.0f)*32.0f - 0.5f;
        float x0f = floorf(gx), y0f = floorf(gy);
        float wx = gx - x0f, wy = gy - y0f;
        int ix = (int)x0f, iy = (int)y0f;
        bool vx0 = (unsigned)ix       < (unsigned)Ww;
        bool vx1 = (unsigned)(ix + 1) < (unsigned)Ww;
        bool vy0 = (unsigned)iy       < (unsigned)Hh;
        bool vy1 = (unsigned)(iy + 1) < (unsigned)Hh;
        int ix0 = min(max(ix, 0), Ww-1), ix1 = min(max(ix+1, 0), Ww-1);
        int iy0 = min(max(iy, 0), Hh-1), iy1 = min(max(iy+1, 0), Hh-1);
        swgt[wv][0][s] = (vx0 && vy0) ? w*(1.0f-wx)*(1.0f-wy) : 0.0f;
        swgt[wv][1][s] = (vx1 && vy0) ? w*wx*(1.0f-wy)        : 0.0f;
        swgt[wv][2][s] = (vx0 && vy1) ? w*(1.0f-wx)*wy        : 0.0f;
        swgt[wv][3][s] = (vx1 && vy1) ? w*wx*wy               : 0.0f;
        soff[wv][0][s] = (iy0*Ww + ix0) * 64;
        soff[wv][1][s] = (iy0*Ww + ix1) * 64;
        soff[wv][2][s] = (iy1*Ww + ix0) * 64;
        soff[wv][3][s] = (iy1*Ww + ix1) * 64;
    }
    __syncthreads();
    int cg   = lane >> 5;
    int head = (lane >> 2) & 7;
    int oc   = lane & 3;
    const char* vbase = (const char*)val + (size_t)(b*Nn*HEADS + head)*HW*64 + oc*16;
    float a[8] = {0.f,0.f,0.f,0.f,0.f,0.f,0.f,0.f};
#pragma unroll
    for (int n = 0; n < Nn; ++n) {
        const char* vb = vbase + (size_t)n*HEADS*HW*64;
#pragma unroll
        for (int p = 0; p < POINTS; ++p) {
            int s = (n*HEADS + head)*POINTS + p;
            float w0 = swgt[wv][cg*2+0][s];
            float w1 = swgt[wv][cg*2+1][s];
            int   o0 = soff[wv][cg*2+0][s];
            int   o1 = soff[wv][cg*2+1][s];
            uint4 u0 = *(const uint4*)(vb + o0);
            uint4 u1 = *(const uint4*)(vb + o1);
            a[0] += w0*bflo(u0.x); a[1] += w0*bfhi(u0.x);
            a[2] += w0*bflo(u0.y); a[3] += w0*bfhi(u0.y);
            a[4] += w0*bflo(u0.z); a[5] += w0*bfhi(u0.z);
            a[6] += w0*bflo(u0.w); a[7] += w0*bfhi(u0.w);
            a[0] += w1*bflo(u1.x); a[1] += w1*bfhi(u1.x);
            a[2] += w1*bflo(u1.y); a[3] += w1*bfhi(u1.y);
            a[4] += w1*bflo(u1.z); a[5] += w1*bfhi(u1.z);
            a[6] += w1*bflo(u1.w); a[7] += w1*bfhi(u1.w);
        }
    }
#pragma unroll
    for (int j = 0; j < 8; ++j) a[j] += __shfl_xor(a[j], 32);
    if (cg == 0) {
        int c = head*32 + oc*8;
        uint4 o;
        o.x = packbf(a[0], a[1]);
        o.y = packbf(a[2], a[3]);
        o.z = packbf(a[4], a[5]);
        o.w = packbf(a[6], a[7]);
        *(uint4*)&wsum[(size_t)q*256 + c] = o;
    }
}

// ---------------------------------------------------------------------------
// Kernel O (MFMA): out = wsum(bf16) @ W_out + b_out. Frag-linear Wotf.
// ---------------------------------------------------------------------------
__global__ __launch_bounds__(256) void out_mfma_kernel(const unsigned short* __restrict__ wsum,
                                                       const unsigned short* __restrict__ Wotf,
                                                       const float* __restrict__ b_out,
                                                       float* __restrict__ out) {
    int t = threadIdx.x;
    int row0 = blockIdx.x * 64;
    int col0 = blockIdx.y * 128;
    int wave = t >> 6, lane = t & 63, quad = lane >> 4, l15 = lane & 15;
    int wm = wave & 1;
    int wn = wave >> 1;
    f32x4 acc[2][4];
#pragma unroll
    for (int i = 0; i < 2; ++i)
#pragma unroll
        for (int j = 0; j < 4; ++j) acc[i][j] = (f32x4){0.f, 0.f, 0.f, 0.f};
#pragma unroll
    for (int kk = 0; kk < 8; ++kk) {
        short8 a[2];
#pragma unroll
        for (int mt = 0; mt < 2; ++mt)
            a[mt] = *(const short8*)&wsum[(size_t)(row0 + wm*32 + mt*16 + l15)*256 + kk*32 + quad*8];
#pragma unroll
        for (int nt = 0; nt < 4; ++nt) {
            size_t fb = ((size_t)((blockIdx.y*8 + wn*4 + nt)*8 + kk) << 9) + lane*8;
            short8 bfr = *(const short8*)&Wotf[fb];
            acc[0][nt] = __builtin_amdgcn_mfma_f32_16x16x32_bf16(a[0], bfr, acc[0][nt], 0, 0, 0);
            acc[1][nt] = __builtin_amdgcn_mfma_f32_16x16x32_bf16(a[1], bfr, acc[1][nt], 0, 0, 0);
        }
    }
#pragma unroll
    for (int nt = 0; nt < 4; ++nt) {
        int col = col0 + wn*64 + nt*16 + l15;
        float bias = b_out[col];
#pragma unroll
        for (int mt = 0; mt < 2; ++mt) {
#pragma unroll
            for (int r = 0; r < 4; ++r) {
                int q = row0 + wm*32 + mt*16 + quad*4 + r;
                out[(size_t)q*256 + col] = acc[mt][nt][r] + bias;
            }
        }
    }
}

extern "C" void kernel_launch(void* const* d_in, const int* in_sizes, int n_in,
                              void* d_out, int out_size, void* d_ws, size_t ws_size,
                              hipStream_t stream) {
    const float* query  = (const float*)d_in[0];
    const float* qc     = (const float*)d_in[1];
    const float* feats  = (const float*)d_in[2];
    const float* intr   = (const float*)d_in[3];
    const float* invE   = (const float*)d_in[4];
    const float* W_off  = (const float*)d_in[5];
    const float* b_off  = (const float*)d_in[6];
    const float* W_attn = (const float*)d_in[7];
    const float* b_attn = (const float*)d_in[8];
    const float* W_val  = (const float*)d_in[9];
    const float* b_val  = (const float*)d_in[10];
    const float* W_out  = (const float*)d_in[11];
    const float* b_out  = (const float*)d_in[12];
    float* out = (float*)d_out;
    float* ws  = (float*)d_ws;
    unsigned short* val  = (unsigned short*)(ws + WS_VAL);
    unsigned short* Wtf  = (unsigned short*)(ws + WS_WTF);
    unsigned short* Wchf = (unsigned short*)(ws + WS_WCHF);
    unsigned short* Wclf = (unsigned short*)(ws + WS_WCLF);
    unsigned short* Wotf = (unsigned short*)(ws + WS_WOTF);
    float* locs = ws + WS_LOCS;
    float* aw   = ws + WS_AW;
    float* reff = ws + WS_REFF;
    unsigned short* wsum = (unsigned short*)(ws + WS_WSUM);
    int* hist = (int*)(ws + WS_HIST);
    int* boff = (int*)(ws + WS_BOFF);
    int* bin  = (int*)(ws + WS_BIN);
    int* perm = (int*)(ws + WS_PERM);

    hipMemsetAsync(hist, 0, 2048*sizeof(int), stream);
    hipLaunchKernelGGL(bin_kernel, dim3(BQ/256), dim3(256), 0, stream,
                       qc, hist, bin);
    hipLaunchKernelGGL(scan_kernel, dim3(1), dim3(256), 0, stream,
                       hist, boff);
    hipLaunchKernelGGL(scatter_kernel, dim3(BQ/256), dim3(256), 0, stream,
                       bin, boff, perm);
    hipLaunchKernelGGL(prep_kernel, dim3(1120), dim3(256), 0, stream,
                       qc, intr, invE, reff, W_val, W_off, W_attn, W_out,
                       Wtf, Wchf, Wclf, Wotf);
    hipLaunchKernelGGL(vp_mfma_kernel, dim3(HW/64, Bb*Nn), dim3(512), 0, stream,
                       feats, Wtf, b_val, val);
    hipLaunchKernelGGL(qp_kernel, dim3(BQ/32, 3), dim3(512), 0, stream,
                       query, Wchf, Wclf, b_off, b_attn, reff, locs, aw);
    hipLaunchKernelGGL(samp_kernel, dim3(BQ/4), dim3(256), 0, stream,
                       val, locs, aw, perm, wsum);
    hipLaunchKernelGGL(out_mfma_kernel, dim3(BQ/64, 2), dim3(256), 0, stream,
                       wsum, Wotf, b_out, out);
}

// Round 9
// 229.370 us; speedup vs baseline: 1.1198x; 1.1198x over previous
//
#include <hip/hip_runtime.h>
#include <math.h>

#define Bb 2
#define Qq 4096
#define Cc 256
#define Nn 6
#define Hh 64
#define Ww 96
#define HEADS 8
#define POINTS 4
#define HW (Hh*Ww)            // 6144
#define BQ (Bb*Qq)            // 8192

// workspace layout (float offsets)
#define WS_VAL   0             // bf16 val [B,N,HEADS,H,W,32] : 18,874,368 sh
#define WS_WTF   9437184       // bf16 W_val^T frag-linear : 65,536 sh
#define WS_WCHF  9469952       // bf16 Wcat^T hi frag-linear: 147,456 sh
#define WS_WCLF  9543680       // bf16 Wcat^T lo frag-linear
#define WS_WOTF  9617408       // bf16 W_out^T frag-linear : 65,536 sh
#define WS_LOCS  18874368      // f32 [B,Q,384]
#define WS_AW    22020096      // f32 [B,Q,192]
#define WS_REFF  23592960      // f32 [B,N,Q,3]
#define WS_WSUM  23740416      // bf16 [B,Q,C] : 1,048,576 fl
#define WS_HIST  24788992      // int[4096]
#define WS_BOFF  24793088      // int[4096]
#define WS_BIN   24797184      // int[8192]
#define WS_PERM  24805376      // int[8192]

typedef __attribute__((ext_vector_type(8))) short short8;
typedef __attribute__((ext_vector_type(4))) float f32x4;

__device__ __forceinline__ unsigned short f2bf(float f) {
    union { float f; unsigned u; } v; v.f = f;
    unsigned r = (v.u + 0x7fffu + ((v.u >> 16) & 1u)) >> 16;
    return (unsigned short)r;
}
__device__ __forceinline__ float bf2f(unsigned short h) { return __uint_as_float((unsigned)h << 16); }
__device__ __forceinline__ float bflo(unsigned u) { return __uint_as_float(u << 16); }
__device__ __forceinline__ float bfhi(unsigned u) { return __uint_as_float(u & 0xffff0000u); }
__device__ __forceinline__ unsigned packbf(float a, float b) {
    return (unsigned)f2bf(a) | ((unsigned)f2bf(b) << 16);
}

// ---------------------------------------------------------------------------
// Kernel PREP: blocks [0,32): fisheye ref+fov.  blocks [32,1120): weight
// casts into MFMA-fragment-linear layouts.
// ---------------------------------------------------------------------------
__global__ void prep_kernel(const float* __restrict__ qc,
                            const float* __restrict__ intr,
                            const float* __restrict__ invE,
                            float* __restrict__ reff,
                            const float* __restrict__ Wv,
                            const float* __restrict__ Wo,
                            const float* __restrict__ Wa,
                            const float* __restrict__ Wu,
                            unsigned short* __restrict__ Wtf,
                            unsigned short* __restrict__ Wchf,
                            unsigned short* __restrict__ Wclf,
                            unsigned short* __restrict__ Wotf) {
    int blk = blockIdx.x;
    int tid = threadIdx.x;
    if (blk < 32) {
        int idx = blk * 256 + tid;
        int b = idx >> 12;
        int q = idx & (Qq - 1);
        float rx = qc[idx*3+0] * 7.2f - 3.6f;
        float ry = qc[idx*3+1] * 6.0f - 3.0f;
        float rz = qc[idx*3+2] * 3.2f - 0.7f;
        for (int n = 0; n < Nn; ++n) {
            const float* E = invE + (b*Nn+n)*16;
            float camx = E[0]*rx + E[1]*ry + E[2]*rz  + E[3];
            float camy = E[4]*rx + E[5]*ry + E[6]*rz  + E[7];
            float camz = E[8]*rx + E[9]*ry + E[10]*rz + E[11];
            const float* K = intr + (b*Nn+n)*9;
            float fx = K[0], cx0 = K[2], cy0 = K[5];
            float r3d   = sqrtf(camx*camx + camy*camy + 1e-8f);
            float theta = atan2f(r3d, camz);
            float phi   = atan2f(camy, camx);
            float r_img = fx * theta;
            float u = r_img * cosf(phi) + cx0;
            float v = r_img * sinf(phi) + cy0;
            int base = ((b*Nn+n)*Qq + q)*3;
            reff[base+0] = 2.0f * u / 1279.0f - 1.0f;
            reff[base+1] = 2.0f * v / 1079.0f - 1.0f;
            reff[base+2] = (camz > 0.0f && theta < 1.372f) ? 1.0f : 0.0f;
        }
        return;
    }
    int idx = (blk - 32) * 256 + tid;     // [0, 278528)
    if (idx < 65536) {
        int s = idx & 7, l = (idx >> 3) & 63, kk = (idx >> 9) & 7, t = idx >> 12;
        int n = t*16 + (l & 15);
        int k = kk*32 + (l >> 4)*8 + s;
        Wtf[idx] = f2bf(Wv[k*256 + n]);
    } else if (idx < 212992) {
        int i2 = idx - 65536;
        int s = i2 & 7, l = (i2 >> 3) & 63, kk = (i2 >> 9) & 7, t = i2 >> 12;
        int n = t*16 + (l & 15);
        int k = kk*32 + (l >> 4)*8 + s;
        float w = (n < 384) ? Wo[k*384 + n] : Wa[k*192 + (n - 384)];
        unsigned short h = f2bf(w);
        Wchf[i2] = h;
        Wclf[i2] = f2bf(w - bf2f(h));
    } else {
        int i3 = idx - 212992;
        int s = i3 & 7, l = (i3 >> 3) & 63, kk = (i3 >> 9) & 7, t = i3 >> 12;
        int n = t*16 + (l & 15);
        int k = kk*32 + (l >> 4)*8 + s;
        Wotf[i3] = f2bf(Wu[k*256 + n]);
    }
}

// ---------------------------------------------------------------------------
// Spatial binning: 4096 bins = (batch, z8, y16, x16) -- batches SEPARATED.
// Counting sort -> perm. samp reads chunk-interleaved for XCD pinning.
// ---------------------------------------------------------------------------
__global__ void bin_kernel(const float* __restrict__ qc,
                           int* __restrict__ hist, int* __restrict__ bin) {
    int q = blockIdx.x*256 + threadIdx.x;        // 8192
    float x = qc[q*3+0], y = qc[q*3+1], z = qc[q*3+2];
    int bx = min(15, max(0, (int)(x*16.f)));
    int by = min(15, max(0, (int)(y*16.f)));
    int bz = min(7,  max(0, (int)(z*8.f)));
    int b = q >> 12;
    int bn = ((b*8 + bz)*16 + by)*16 + bx;       // [0, 4096)
    bin[q] = bn;
    atomicAdd(&hist[bn], 1);
}

__global__ void scan_kernel(const int* __restrict__ hist, int* __restrict__ boff) {
    __shared__ int psum[256];
    int t = threadIdx.x;
    int loc[16]; int s = 0;
#pragma unroll
    for (int i = 0; i < 16; ++i) { loc[i] = hist[t*16+i]; s += loc[i]; }
    psum[t] = s;
    __syncthreads();
    for (int off = 1; off < 256; off <<= 1) {
        int v = (t >= off) ? psum[t-off] : 0;
        __syncthreads();
        psum[t] += v;
        __syncthreads();
    }
    int base = (t == 0) ? 0 : psum[t-1];
#pragma unroll
    for (int i = 0; i < 16; ++i) { boff[t*16+i] = base; base += loc[i]; }
}

__global__ void scatter_kernel(const int* __restrict__ bin,
                               int* __restrict__ boff, int* __restrict__ perm) {
    int q = blockIdx.x*256 + threadIdx.x;
    int pos = atomicAdd(&boff[bin[q]], 1);
    perm[pos] = q;
}

// ---------------------------------------------------------------------------
// Kernel VP (MFMA): value projection -> val in HEAD-MAJOR layout:
// val[b,n,head,h,w,32ch].
// ---------------------------------------------------------------------------
__global__ __launch_bounds__(512, 2) void vp_mfma_kernel(const float* __restrict__ feats,
                                                         const unsigned short* __restrict__ Wtf,
                                                         const float* __restrict__ bv,
                                                         unsigned short* __restrict__ val) {
    __shared__ __align__(16) unsigned short As[64 * 272];   // 34.8 KB
    int t = threadIdx.x;
    int pix0 = blockIdx.x * 64;
    int bn = blockIdx.y;
    const float* A = feats + (size_t)bn * Cc * HW + pix0;
    int lane = t & 63, wavei = t >> 6, quad = lane >> 4, l15 = lane & 15;
    {
        int pq = t & 15;
        int oct = t >> 4;
        float va[8][4];
#pragma unroll
        for (int j = 0; j < 8; ++j)
            *(float4*)va[j] = *(const float4*)&A[(size_t)(oct*8 + j)*HW + pq*4];
#pragma unroll
        for (int e = 0; e < 4; ++e) {
            int m = pq*4 + e;
            uint4 pk;
            pk.x = packbf(va[0][e], va[1][e]);
            pk.y = packbf(va[2][e], va[3][e]);
            pk.z = packbf(va[4][e], va[5][e]);
            pk.w = packbf(va[6][e], va[7][e]);
            *(uint4*)&As[m*264 + oct*8] = pk;
        }
    }
    __syncthreads();
    int wm = wavei & 1;
    int wn = wavei >> 1;
    int r0 = wm*32 + l15, r1 = r0 + 16;
    const unsigned short* Wl = Wtf + (size_t)lane * 8;
#define VP_BOFF(nt, kk) ((size_t)(((wn*4 + (nt))*8 + (kk)) << 9))
    f32x4 acc[2][4];
#pragma unroll
    for (int i = 0; i < 2; ++i)
#pragma unroll
        for (int j = 0; j < 4; ++j) acc[i][j] = (f32x4){0.f, 0.f, 0.f, 0.f};
    short8 bA[4], bB[4];
#pragma unroll
    for (int nt = 0; nt < 4; ++nt) bA[nt] = *(const short8*)&Wl[VP_BOFF(nt, 0)];
#pragma unroll
    for (int kk = 0; kk < 8; kk += 2) {
        if (kk + 1 < 8) {
#pragma unroll
            for (int nt = 0; nt < 4; ++nt) bB[nt] = *(const short8*)&Wl[VP_BOFF(nt, kk+1)];
        }
        {
            short8 a0 = *(const short8*)&As[r0*264 + kk*32 + quad*8];
            short8 a1 = *(const short8*)&As[r1*264 + kk*32 + quad*8];
#pragma unroll
            for (int nt = 0; nt < 4; ++nt) {
                acc[0][nt] = __builtin_amdgcn_mfma_f32_16x16x32_bf16(a0, bA[nt], acc[0][nt], 0, 0, 0);
                acc[1][nt] = __builtin_amdgcn_mfma_f32_16x16x32_bf16(a1, bA[nt], acc[1][nt], 0, 0, 0);
            }
        }
        if (kk + 2 < 8) {
#pragma unroll
            for (int nt = 0; nt < 4; ++nt) bA[nt] = *(const short8*)&Wl[VP_BOFF(nt, kk+2)];
        }
        if (kk + 1 < 8) {
            int k1 = kk + 1;
            short8 a0 = *(const short8*)&As[r0*264 + k1*32 + quad*8];
            short8 a1 = *(const short8*)&As[r1*264 + k1*32 + quad*8];
#pragma unroll
            for (int nt = 0; nt < 4; ++nt) {
                acc[0][nt] = __builtin_amdgcn_mfma_f32_16x16x32_bf16(a0, bB[nt], acc[0][nt], 0, 0, 0);
                acc[1][nt] = __builtin_amdgcn_mfma_f32_16x16x32_bf16(a1, bB[nt], acc[1][nt], 0, 0, 0);
            }
        }
    }
    __syncthreads();
#pragma unroll
    for (int nt = 0; nt < 4; ++nt) {
        int n = wn*64 + nt*16 + l15;
        float bias = bv[n];
#pragma unroll
        for (int mt = 0; mt < 2; ++mt) {
#pragma unroll
            for (int r = 0; r < 4; ++r) {
                int mm = wm*32 + mt*16 + quad*4 + r;
                As[mm*272 + n] = f2bf(acc[mt][nt][r] + bias);
            }
        }
    }
    __syncthreads();
#pragma unroll
    for (int i = 0; i < 4; ++i) {
        int flat = wavei*2048 + i*512 + lane*8;    // shorts
        int pix = flat >> 8, ch = flat & 255;
        int head = ch >> 5, c32 = ch & 31;
        *(uint4*)&val[(((size_t)bn*HEADS + head)*HW + pix0 + pix)*32 + c32] =
            *(const uint4*)&As[pix*272 + ch];
    }
}

// ---------------------------------------------------------------------------
// Kernel QP: fused query projection.
// ---------------------------------------------------------------------------
__global__ __launch_bounds__(512, 4) void qp_kernel(const float* __restrict__ query,
                                                    const unsigned short* __restrict__ Wchf,
                                                    const unsigned short* __restrict__ Wclf,
                                                    const float* __restrict__ b_off,
                                                    const float* __restrict__ b_attn,
                                                    const float* __restrict__ reff,
                                                    float* __restrict__ locs,
                                                    float* __restrict__ aw) {
    __shared__ __align__(16) unsigned short Ah[32 * 256];   // 16 KB
    __shared__ __align__(16) unsigned short Al[32 * 256];   // 16 KB
    int t = threadIdx.x;
    int row0 = blockIdx.x * 32;
    int ty = blockIdx.y;
    {
        int row = t & 31;
        int c2 = t >> 5;
        const float* src = query + (size_t)(row0 + row) * 256;
#pragma unroll
        for (int cc = 0; cc < 2; ++cc) {
            int c = c2 * 2 + cc;
            float4 v0 = *(const float4*)&src[c*8 + 0];
            float4 v1 = *(const float4*)&src[c*8 + 4];
            float f[8] = {v0.x, v0.y, v0.z, v0.w, v1.x, v1.y, v1.z, v1.w};
            unsigned short h[8], l[8];
#pragma unroll
            for (int j = 0; j < 8; ++j) {
                h[j] = f2bf(f[j]);
                l[j] = f2bf(f[j] - bf2f(h[j]));
            }
            uint4 ph, pl;
            ph.x = h[0] | ((unsigned)h[1] << 16); ph.y = h[2] | ((unsigned)h[3] << 16);
            ph.z = h[4] | ((unsigned)h[5] << 16); ph.w = h[6] | ((unsigned)h[7] << 16);
            pl.x = l[0] | ((unsigned)l[1] << 16); pl.y = l[2] | ((unsigned)l[3] << 16);
            pl.z = l[4] | ((unsigned)l[5] << 16); pl.w = l[6] | ((unsigned)l[7] << 16);
            int pos = row * 256 + ((c ^ row) << 3);
            *(uint4*)&Ah[pos] = ph;
            *(uint4*)&Al[pos] = pl;
        }
    }
    __syncthreads();
    int wave = t >> 6, lane = t & 63, quad = lane >> 4, l15 = lane & 15;
    int ms = wave & 1;
    int ng = wave >> 1;
    int arow = ms*16 + l15;
    int bq = row0 >> 12;
    int tile0 = ty*12 + ng*3;
    f32x4 acc[3];
#pragma unroll
    for (int i = 0; i < 3; ++i) acc[i] = (f32x4){0.f, 0.f, 0.f, 0.f};

#define QP_FB(i, kk) (((size_t)((tile0 + (i))*8 + (kk)) << 9) + lane*8)

    if (ty < 2) {
        short8 bhA[3], blA[3], bhB[3], blB[3];
#pragma unroll
        for (int i = 0; i < 3; ++i) {
            bhA[i] = *(const short8*)&Wchf[QP_FB(i, 0)];
            blA[i] = *(const short8*)&Wclf[QP_FB(i, 0)];
        }
#pragma unroll
        for (int kk = 0; kk < 8; kk += 2) {
            if (kk + 1 < 8) {
#pragma unroll
                for (int i = 0; i < 3; ++i) {
                    bhB[i] = *(const short8*)&Wchf[QP_FB(i, kk+1)];
                    blB[i] = *(const short8*)&Wclf[QP_FB(i, kk+1)];
                }
            }
            {
                int apos = arow*256 + (((kk*4+quad) ^ arow) << 3);
                short8 a_h = *(const short8*)&Ah[apos];
                short8 a_l = *(const short8*)&Al[apos];
#pragma unroll
                for (int i = 0; i < 3; ++i) {
                    acc[i] = __builtin_amdgcn_mfma_f32_16x16x32_bf16(a_h, bhA[i], acc[i], 0, 0, 0);
                    acc[i] = __builtin_amdgcn_mfma_f32_16x16x32_bf16(a_l, bhA[i], acc[i], 0, 0, 0);
                    acc[i] = __builtin_amdgcn_mfma_f32_16x16x32_bf16(a_h, blA[i], acc[i], 0, 0, 0);
                }
            }
            if (kk + 2 < 8) {
#pragma unroll
                for (int i = 0; i < 3; ++i) {
                    bhA[i] = *(const short8*)&Wchf[QP_FB(i, kk+2)];
                    blA[i] = *(const short8*)&Wclf[QP_FB(i, kk+2)];
                }
            }
            if (kk + 1 < 8) {
                int k1 = kk + 1;
                int apos = arow*256 + (((k1*4+quad) ^ arow) << 3);
                short8 a_h = *(const short8*)&Ah[apos];
                short8 a_l = *(const short8*)&Al[apos];
#pragma unroll
                for (int i = 0; i < 3; ++i) {
                    acc[i] = __builtin_amdgcn_mfma_f32_16x16x32_bf16(a_h, bhB[i], acc[i], 0, 0, 0);
                    acc[i] = __builtin_amdgcn_mfma_f32_16x16x32_bf16(a_l, bhB[i], acc[i], 0, 0, 0);
                    acc[i] = __builtin_amdgcn_mfma_f32_16x16x32_bf16(a_h, blB[i], acc[i], 0, 0, 0);
                }
            }
        }
#pragma unroll
        for (int i = 0; i < 3; ++i) {
            int j = (tile0 + i)*16 + l15;
            int n_cam = j >> 6;
            int xy = j & 1;
            float bias = b_off[j];
#pragma unroll
            for (int r = 0; r < 4; ++r) {
                int q = row0 + ms*16 + quad*4 + r;
                int qq = q & (Qq-1);
                float refv = reff[((bq*Nn + n_cam)*Qq + qq)*3 + xy];
                locs[(size_t)q*384 + j] = refv + tanhf(acc[i][r] + bias) * 0.5f;
            }
        }
    } else {
        short8 bhA[3], bhB[3];
#pragma unroll
        for (int i = 0; i < 3; ++i) bhA[i] = *(const short8*)&Wchf[QP_FB(i, 0)];
#pragma unroll
        for (int kk = 0; kk < 8; kk += 2) {
            if (kk + 1 < 8) {
#pragma unroll
                for (int i = 0; i < 3; ++i) bhB[i] = *(const short8*)&Wchf[QP_FB(i, kk+1)];
            }
            {
                int apos = arow*256 + (((kk*4+quad) ^ arow) << 3);
                short8 a_h = *(const short8*)&Ah[apos];
#pragma unroll
                for (int i = 0; i < 3; ++i)
                    acc[i] = __builtin_amdgcn_mfma_f32_16x16x32_bf16(a_h, bhA[i], acc[i], 0, 0, 0);
            }
            if (kk + 2 < 8) {
#pragma unroll
                for (int i = 0; i < 3; ++i) bhA[i] = *(const short8*)&Wchf[QP_FB(i, kk+2)];
            }
            if (kk + 1 < 8) {
                int k1 = kk + 1;
                int apos = arow*256 + (((k1*4+quad) ^ arow) << 3);
                short8 a_h = *(const short8*)&Ah[apos];
#pragma unroll
                for (int i = 0; i < 3; ++i)
                    acc[i] = __builtin_amdgcn_mfma_f32_16x16x32_bf16(a_h, bhB[i], acc[i], 0, 0, 0);
            }
        }
#pragma unroll
        for (int i = 0; i < 3; ++i) {
            int j2 = (tile0 + i)*16 + l15 - 384;
            int n_cam = j2 >> 5;
            float bias = b_attn[j2];
#pragma unroll
            for (int r = 0; r < 4; ++r) {
                int q = row0 + ms*16 + quad*4 + r;
                int qq = q & (Qq-1);
                float fov = reff[((bq*Nn + n_cam)*Qq + qq)*3 + 2];
                float lg = (acc[i][r] + bias) * fov;
                float mx = fmaxf(lg, __shfl_xor(lg, 1));
                mx = fmaxf(mx, __shfl_xor(mx, 2));
                float e = expf(lg - mx);
                float s = e + __shfl_xor(e, 1);
                s = s + __shfl_xor(s, 2);
                aw[(size_t)q*192 + j2] = e / s;
            }
        }
    }
#undef QP_FB
}

// ---------------------------------------------------------------------------
// Kernel S: bilinear sampling + weighted sum -> wsum (bf16).
// 512 thr = 8 waves = 8 co-binned queries (guaranteed same-XCD reuse).
// Block bi draws from sorted chunk (bi&7) at position bi>>3 -> with %8
// round-robin dispatch each XCD sweeps one contiguous 1/8 of the sort
// (~4.7 MB val footprint = fits private 4 MB L2).
// ---------------------------------------------------------------------------
__global__ __launch_bounds__(512, 4) void samp_kernel(const unsigned short* __restrict__ val,
                                                      const float* __restrict__ locs,
                                                      const float* __restrict__ aw,
                                                      const int* __restrict__ perm,
                                                      unsigned short* __restrict__ wsum) {
    __shared__ float swgt[8][4][196];
    __shared__ int   soff[8][4][196];
    int t = threadIdx.x, wv = t >> 6, lane = t & 63;
    int bi = blockIdx.x;
    int q = perm[(bi & 7) * 1024 + (bi >> 3) * 8 + wv];
    int b = q >> 12;
#pragma unroll
    for (int j = 0; j < 3; ++j) {
        int s = lane + 64*j;
        float2 xy = *(const float2*)&locs[(size_t)q*384 + 2*s];
        float w = aw[(size_t)q*192 + s];
        float gx = (xy.x + 1.0f)*48.0f - 0.5f;
        float gy = (xy.y + 1.0f)*32.0f - 0.5f;
        float x0f = floorf(gx), y0f = floorf(gy);
        float wx = gx - x0f, wy = gy - y0f;
        int ix = (int)x0f, iy = (int)y0f;
        bool vx0 = (unsigned)ix       < (unsigned)Ww;
        bool vx1 = (unsigned)(ix + 1) < (unsigned)Ww;
        bool vy0 = (unsigned)iy       < (unsigned)Hh;
        bool vy1 = (unsigned)(iy + 1) < (unsigned)Hh;
        int ix0 = min(max(ix, 0), Ww-1), ix1 = min(max(ix+1, 0), Ww-1);
        int iy0 = min(max(iy, 0), Hh-1), iy1 = min(max(iy+1, 0), Hh-1);
        swgt[wv][0][s] = (vx0 && vy0) ? w*(1.0f-wx)*(1.0f-wy) : 0.0f;
        swgt[wv][1][s] = (vx1 && vy0) ? w*wx*(1.0f-wy)        : 0.0f;
        swgt[wv][2][s] = (vx0 && vy1) ? w*(1.0f-wx)*wy        : 0.0f;
        swgt[wv][3][s] = (vx1 && vy1) ? w*wx*wy               : 0.0f;
        soff[wv][0][s] = (iy0*Ww + ix0) * 64;
        soff[wv][1][s] = (iy0*Ww + ix1) * 64;
        soff[wv][2][s] = (iy1*Ww + ix0) * 64;
        soff[wv][3][s] = (iy1*Ww + ix1) * 64;
    }
    __syncthreads();
    int cg   = lane >> 5;
    int head = (lane >> 2) & 7;
    int oc   = lane & 3;
    const char* vbase = (const char*)val + (size_t)(b*Nn*HEADS + head)*HW*64 + oc*16;
    float a[8] = {0.f,0.f,0.f,0.f,0.f,0.f,0.f,0.f};
#pragma unroll
    for (int n = 0; n < Nn; ++n) {
        const char* vb = vbase + (size_t)n*HEADS*HW*64;
#pragma unroll
        for (int p = 0; p < POINTS; ++p) {
            int s = (n*HEADS + head)*POINTS + p;
            float w0 = swgt[wv][cg*2+0][s];
            float w1 = swgt[wv][cg*2+1][s];
            int   o0 = soff[wv][cg*2+0][s];
            int   o1 = soff[wv][cg*2+1][s];
            uint4 u0 = *(const uint4*)(vb + o0);
            uint4 u1 = *(const uint4*)(vb + o1);
            a[0] += w0*bflo(u0.x); a[1] += w0*bfhi(u0.x);
            a[2] += w0*bflo(u0.y); a[3] += w0*bfhi(u0.y);
            a[4] += w0*bflo(u0.z); a[5] += w0*bfhi(u0.z);
            a[6] += w0*bflo(u0.w); a[7] += w0*bfhi(u0.w);
            a[0] += w1*bflo(u1.x); a[1] += w1*bfhi(u1.x);
            a[2] += w1*bflo(u1.y); a[3] += w1*bfhi(u1.y);
            a[4] += w1*bflo(u1.z); a[5] += w1*bfhi(u1.z);
            a[6] += w1*bflo(u1.w); a[7] += w1*bfhi(u1.w);
        }
    }
#pragma unroll
    for (int j = 0; j < 8; ++j) a[j] += __shfl_xor(a[j], 32);
    if (cg == 0) {
        int c = head*32 + oc*8;
        uint4 o;
        o.x = packbf(a[0], a[1]);
        o.y = packbf(a[2], a[3]);
        o.z = packbf(a[4], a[5]);
        o.w = packbf(a[6], a[7]);
        *(uint4*)&wsum[(size_t)q*256 + c] = o;
    }
}

// ---------------------------------------------------------------------------
// Kernel O (MFMA): out = wsum(bf16) @ W_out + b_out. Frag-linear Wotf.
// ---------------------------------------------------------------------------
__global__ __launch_bounds__(256) void out_mfma_kernel(const unsigned short* __restrict__ wsum,
                                                       const unsigned short* __restrict__ Wotf,
                                                       const float* __restrict__ b_out,
                                                       float* __restrict__ out) {
    int t = threadIdx.x;
    int row0 = blockIdx.x * 64;
    int col0 = blockIdx.y * 128;
    int wave = t >> 6, lane = t & 63, quad = lane >> 4, l15 = lane & 15;
    int wm = wave & 1;
    int wn = wave >> 1;
    f32x4 acc[2][4];
#pragma unroll
    for (int i = 0; i < 2; ++i)
#pragma unroll
        for (int j = 0; j < 4; ++j) acc[i][j] = (f32x4){0.f, 0.f, 0.f, 0.f};
#pragma unroll
    for (int kk = 0; kk < 8; ++kk) {
        short8 a[2];
#pragma unroll
        for (int mt = 0; mt < 2; ++mt)
            a[mt] = *(const short8*)&wsum[(size_t)(row0 + wm*32 + mt*16 + l15)*256 + kk*32 + quad*8];
#pragma unroll
        for (int nt = 0; nt < 4; ++nt) {
            size_t fb = ((size_t)((blockIdx.y*8 + wn*4 + nt)*8 + kk) << 9) + lane*8;
            short8 bfr = *(const short8*)&Wotf[fb];
            acc[0][nt] = __builtin_amdgcn_mfma_f32_16x16x32_bf16(a[0], bfr, acc[0][nt], 0, 0, 0);
            acc[1][nt] = __builtin_amdgcn_mfma_f32_16x16x32_bf16(a[1], bfr, acc[1][nt], 0, 0, 0);
        }
    }
#pragma unroll
    for (int nt = 0; nt < 4; ++nt) {
        int col = col0 + wn*64 + nt*16 + l15;
        float bias = b_out[col];
#pragma unroll
        for (int mt = 0; mt < 2; ++mt) {
#pragma unroll
            for (int r = 0; r < 4; ++r) {
                int q = row0 + wm*32 + mt*16 + quad*4 + r;
                out[(size_t)q*256 + col] = acc[mt][nt][r] + bias;
            }
        }
    }
}

extern "C" void kernel_launch(void* const* d_in, const int* in_sizes, int n_in,
                              void* d_out, int out_size, void* d_ws, size_t ws_size,
                              hipStream_t stream) {
    const float* query  = (const float*)d_in[0];
    const float* qc     = (const float*)d_in[1];
    const float* feats  = (const float*)d_in[2];
    const float* intr   = (const float*)d_in[3];
    const float* invE   = (const float*)d_in[4];
    const float* W_off  = (const float*)d_in[5];
    const float* b_off  = (const float*)d_in[6];
    const float* W_attn = (const float*)d_in[7];
    const float* b_attn = (const float*)d_in[8];
    const float* W_val  = (const float*)d_in[9];
    const float* b_val  = (const float*)d_in[10];
    const float* W_out  = (const float*)d_in[11];
    const float* b_out  = (const float*)d_in[12];
    float* out = (float*)d_out;
    float* ws  = (float*)d_ws;
    unsigned short* val  = (unsigned short*)(ws + WS_VAL);
    unsigned short* Wtf  = (unsigned short*)(ws + WS_WTF);
    unsigned short* Wchf = (unsigned short*)(ws + WS_WCHF);
    unsigned short* Wclf = (unsigned short*)(ws + WS_WCLF);
    unsigned short* Wotf = (unsigned short*)(ws + WS_WOTF);
    float* locs = ws + WS_LOCS;
    float* aw   = ws + WS_AW;
    float* reff = ws + WS_REFF;
    unsigned short* wsum = (unsigned short*)(ws + WS_WSUM);
    int* hist = (int*)(ws + WS_HIST);
    int* boff = (int*)(ws + WS_BOFF);
    int* bin  = (int*)(ws + WS_BIN);
    int* perm = (int*)(ws + WS_PERM);

    hipMemsetAsync(hist, 0, 4096*sizeof(int), stream);
    hipLaunchKernelGGL(bin_kernel, dim3(BQ/256), dim3(256), 0, stream,
                       qc, hist, bin);
    hipLaunchKernelGGL(scan_kernel, dim3(1), dim3(256), 0, stream,
                       hist, boff);
    hipLaunchKernelGGL(scatter_kernel, dim3(BQ/256), dim3(256), 0, stream,
                       bin, boff, perm);
    hipLaunchKernelGGL(prep_kernel, dim3(1120), dim3(256), 0, stream,
                       qc, intr, invE, reff, W_val, W_off, W_attn, W_out,
                       Wtf, Wchf, Wclf, Wotf);
    hipLaunchKernelGGL(vp_mfma_kernel, dim3(HW/64, Bb*Nn), dim3(512), 0, stream,
                       feats, Wtf, b_val, val);
    hipLaunchKernelGGL(qp_kernel, dim3(BQ/32, 3), dim3(512), 0, stream,
                       query, Wchf, Wclf, b_off, b_attn, reff, locs, aw);
    hipLaunchKernelGGL(samp_kernel, dim3(BQ/8), dim3(512), 0, stream,
                       val, locs, aw, perm, wsum);
    hipLaunchKernelGGL(out_mfma_kernel, dim3(BQ/64, 2), dim3(256), 0, stream,
                       wsum, Wotf, b_out, out);
}

// Round 10
// 228.185 us; speedup vs baseline: 1.1256x; 1.0052x over previous
//
#include <hip/hip_runtime.h>
#include <math.h>

#define Bb 2
#define Qq 4096
#define Cc 256
#define Nn 6
#define Hh 64
#define Ww 96
#define HEADS 8
#define POINTS 4
#define HW (Hh*Ww)            // 6144
#define BQ (Bb*Qq)            // 8192

// workspace layout (float offsets)
#define WS_VAL   0             // bf16 val [B,N,HEADS,H,W,32] : 18,874,368 sh
#define WS_WTF   9437184       // bf16 W_val^T frag-linear : 65,536 sh
#define WS_WCHF  9469952       // bf16 Wcat^T hi frag-linear: 147,456 sh
#define WS_WCLF  9543680       // bf16 Wcat^T lo frag-linear
#define WS_WOTF  9617408       // bf16 W_out^T frag-linear : 65,536 sh
#define WS_LOCS  18874368      // f32 [B,Q,384]
#define WS_AW    22020096      // f32 [B,Q,192]
#define WS_REFF  23592960      // f32 [B,N,Q,3]
#define WS_WSUM  23740416      // bf16 [B,Q,C] : 1,048,576 fl
#define WS_HIST  24788992      // int[4096]
#define WS_BOFF  24793088      // int[4096]
#define WS_BIN   24797184      // int[8192]
#define WS_PERM  24805376      // int[8192]

typedef __attribute__((ext_vector_type(8))) short short8;
typedef __attribute__((ext_vector_type(4))) float f32x4;

__device__ __forceinline__ unsigned short f2bf(float f) {
    union { float f; unsigned u; } v; v.f = f;
    unsigned r = (v.u + 0x7fffu + ((v.u >> 16) & 1u)) >> 16;
    return (unsigned short)r;
}
__device__ __forceinline__ float bf2f(unsigned short h) { return __uint_as_float((unsigned)h << 16); }
__device__ __forceinline__ float bflo(unsigned u) { return __uint_as_float(u << 16); }
__device__ __forceinline__ float bfhi(unsigned u) { return __uint_as_float(u & 0xffff0000u); }
__device__ __forceinline__ unsigned packbf(float a, float b) {
    return (unsigned)f2bf(a) | ((unsigned)f2bf(b) << 16);
}

// ---------------------------------------------------------------------------
// Kernel PREP: blocks [0,32): fisheye ref+fov AND spatial binning (snake
// order).  blocks [32,1120): weight casts into MFMA-fragment-linear layouts.
// ---------------------------------------------------------------------------
__global__ void prep_kernel(const float* __restrict__ qc,
                            const float* __restrict__ intr,
                            const float* __restrict__ invE,
                            float* __restrict__ reff,
                            const float* __restrict__ Wv,
                            const float* __restrict__ Wo,
                            const float* __restrict__ Wa,
                            const float* __restrict__ Wu,
                            unsigned short* __restrict__ Wtf,
                            unsigned short* __restrict__ Wchf,
                            unsigned short* __restrict__ Wclf,
                            unsigned short* __restrict__ Wotf,
                            int* __restrict__ hist,
                            int* __restrict__ bin) {
    int blk = blockIdx.x;
    int tid = threadIdx.x;
    if (blk < 32) {
        int idx = blk * 256 + tid;
        int b = idx >> 12;
        int q = idx & (Qq - 1);
        float qx = qc[idx*3+0], qy = qc[idx*3+1], qz = qc[idx*3+2];
        // ---- snake-ordered spatial bin (consecutive bins are adjacent) ----
        {
            int bx = min(15, max(0, (int)(qx*16.f)));
            int by = min(15, max(0, (int)(qy*16.f)));
            int bz = min(7,  max(0, (int)(qz*8.f)));
            if (bz & 1) by = 15 - by;
            if (by & 1) bx = 15 - bx;
            int bn = ((b*8 + bz)*16 + by)*16 + bx;   // [0, 4096)
            bin[idx] = bn;
            atomicAdd(&hist[bn], 1);
        }
        float rx = qx * 7.2f - 3.6f;
        float ry = qy * 6.0f - 3.0f;
        float rz = qz * 3.2f - 0.7f;
        for (int n = 0; n < Nn; ++n) {
            const float* E = invE + (b*Nn+n)*16;
            float camx = E[0]*rx + E[1]*ry + E[2]*rz  + E[3];
            float camy = E[4]*rx + E[5]*ry + E[6]*rz  + E[7];
            float camz = E[8]*rx + E[9]*ry + E[10]*rz + E[11];
            const float* K = intr + (b*Nn+n)*9;
            float fx = K[0], cx0 = K[2], cy0 = K[5];
            float r3d   = sqrtf(camx*camx + camy*camy + 1e-8f);
            float theta = atan2f(r3d, camz);
            float phi   = atan2f(camy, camx);
            float r_img = fx * theta;
            float u = r_img * cosf(phi) + cx0;
            float v = r_img * sinf(phi) + cy0;
            int base = ((b*Nn+n)*Qq + q)*3;
            reff[base+0] = 2.0f * u / 1279.0f - 1.0f;
            reff[base+1] = 2.0f * v / 1079.0f - 1.0f;
            reff[base+2] = (camz > 0.0f && theta < 1.372f) ? 1.0f : 0.0f;
        }
        return;
    }
    int idx = (blk - 32) * 256 + tid;     // [0, 278528)
    if (idx < 65536) {
        int s = idx & 7, l = (idx >> 3) & 63, kk = (idx >> 9) & 7, t = idx >> 12;
        int n = t*16 + (l & 15);
        int k = kk*32 + (l >> 4)*8 + s;
        Wtf[idx] = f2bf(Wv[k*256 + n]);
    } else if (idx < 212992) {
        int i2 = idx - 65536;
        int s = i2 & 7, l = (i2 >> 3) & 63, kk = (i2 >> 9) & 7, t = i2 >> 12;
        int n = t*16 + (l & 15);
        int k = kk*32 + (l >> 4)*8 + s;
        float w = (n < 384) ? Wo[k*384 + n] : Wa[k*192 + (n - 384)];
        unsigned short h = f2bf(w);
        Wchf[i2] = h;
        Wclf[i2] = f2bf(w - bf2f(h));
    } else {
        int i3 = idx - 212992;
        int s = i3 & 7, l = (i3 >> 3) & 63, kk = (i3 >> 9) & 7, t = i3 >> 12;
        int n = t*16 + (l & 15);
        int k = kk*32 + (l >> 4)*8 + s;
        Wotf[i3] = f2bf(Wu[k*256 + n]);
    }
}

__global__ void scan_kernel(const int* __restrict__ hist, int* __restrict__ boff) {
    __shared__ int psum[256];
    int t = threadIdx.x;
    int loc[16]; int s = 0;
#pragma unroll
    for (int i = 0; i < 16; ++i) { loc[i] = hist[t*16+i]; s += loc[i]; }
    psum[t] = s;
    __syncthreads();
    for (int off = 1; off < 256; off <<= 1) {
        int v = (t >= off) ? psum[t-off] : 0;
        __syncthreads();
        psum[t] += v;
        __syncthreads();
    }
    int base = (t == 0) ? 0 : psum[t-1];
#pragma unroll
    for (int i = 0; i < 16; ++i) { boff[t*16+i] = base; base += loc[i]; }
}

__global__ void scatter_kernel(const int* __restrict__ bin,
                               int* __restrict__ boff, int* __restrict__ perm) {
    int q = blockIdx.x*256 + threadIdx.x;
    int pos = atomicAdd(&boff[bin[q]], 1);
    perm[pos] = q;
}

// ---------------------------------------------------------------------------
// Kernel VP (MFMA): value projection -> val in HEAD-MAJOR layout:
// val[b,n,head,h,w,32ch].
// ---------------------------------------------------------------------------
__global__ __launch_bounds__(512, 2) void vp_mfma_kernel(const float* __restrict__ feats,
                                                         const unsigned short* __restrict__ Wtf,
                                                         const float* __restrict__ bv,
                                                         unsigned short* __restrict__ val) {
    __shared__ __align__(16) unsigned short As[64 * 272];   // 34.8 KB
    int t = threadIdx.x;
    int pix0 = blockIdx.x * 64;
    int bn = blockIdx.y;
    const float* A = feats + (size_t)bn * Cc * HW + pix0;
    int lane = t & 63, wavei = t >> 6, quad = lane >> 4, l15 = lane & 15;
    {
        int pq = t & 15;
        int oct = t >> 4;
        float va[8][4];
#pragma unroll
        for (int j = 0; j < 8; ++j)
            *(float4*)va[j] = *(const float4*)&A[(size_t)(oct*8 + j)*HW + pq*4];
#pragma unroll
        for (int e = 0; e < 4; ++e) {
            int m = pq*4 + e;
            uint4 pk;
            pk.x = packbf(va[0][e], va[1][e]);
            pk.y = packbf(va[2][e], va[3][e]);
            pk.z = packbf(va[4][e], va[5][e]);
            pk.w = packbf(va[6][e], va[7][e]);
            *(uint4*)&As[m*264 + oct*8] = pk;
        }
    }
    __syncthreads();
    int wm = wavei & 1;
    int wn = wavei >> 1;
    int r0 = wm*32 + l15, r1 = r0 + 16;
    const unsigned short* Wl = Wtf + (size_t)lane * 8;
#define VP_BOFF(nt, kk) ((size_t)(((wn*4 + (nt))*8 + (kk)) << 9))
    f32x4 acc[2][4];
#pragma unroll
    for (int i = 0; i < 2; ++i)
#pragma unroll
        for (int j = 0; j < 4; ++j) acc[i][j] = (f32x4){0.f, 0.f, 0.f, 0.f};
    short8 bA[4], bB[4];
#pragma unroll
    for (int nt = 0; nt < 4; ++nt) bA[nt] = *(const short8*)&Wl[VP_BOFF(nt, 0)];
#pragma unroll
    for (int kk = 0; kk < 8; kk += 2) {
        if (kk + 1 < 8) {
#pragma unroll
            for (int nt = 0; nt < 4; ++nt) bB[nt] = *(const short8*)&Wl[VP_BOFF(nt, kk+1)];
        }
        {
            short8 a0 = *(const short8*)&As[r0*264 + kk*32 + quad*8];
            short8 a1 = *(const short8*)&As[r1*264 + kk*32 + quad*8];
#pragma unroll
            for (int nt = 0; nt < 4; ++nt) {
                acc[0][nt] = __builtin_amdgcn_mfma_f32_16x16x32_bf16(a0, bA[nt], acc[0][nt], 0, 0, 0);
                acc[1][nt] = __builtin_amdgcn_mfma_f32_16x16x32_bf16(a1, bA[nt], acc[1][nt], 0, 0, 0);
            }
        }
        if (kk + 2 < 8) {
#pragma unroll
            for (int nt = 0; nt < 4; ++nt) bA[nt] = *(const short8*)&Wl[VP_BOFF(nt, kk+2)];
        }
        if (kk + 1 < 8) {
            int k1 = kk + 1;
            short8 a0 = *(const short8*)&As[r0*264 + k1*32 + quad*8];
            short8 a1 = *(const short8*)&As[r1*264 + k1*32 + quad*8];
#pragma unroll
            for (int nt = 0; nt < 4; ++nt) {
                acc[0][nt] = __builtin_amdgcn_mfma_f32_16x16x32_bf16(a0, bB[nt], acc[0][nt], 0, 0, 0);
                acc[1][nt] = __builtin_amdgcn_mfma_f32_16x16x32_bf16(a1, bB[nt], acc[1][nt], 0, 0, 0);
            }
        }
    }
    __syncthreads();
#pragma unroll
    for (int nt = 0; nt < 4; ++nt) {
        int n = wn*64 + nt*16 + l15;
        float bias = bv[n];
#pragma unroll
        for (int mt = 0; mt < 2; ++mt) {
#pragma unroll
            for (int r = 0; r < 4; ++r) {
                int mm = wm*32 + mt*16 + quad*4 + r;
                As[mm*272 + n] = f2bf(acc[mt][nt][r] + bias);
            }
        }
    }
    __syncthreads();
#pragma unroll
    for (int i = 0; i < 4; ++i) {
        int flat = wavei*2048 + i*512 + lane*8;    // shorts
        int pix = flat >> 8, ch = flat & 255;
        int head = ch >> 5, c32 = ch & 31;
        *(uint4*)&val[(((size_t)bn*HEADS + head)*HW + pix0 + pix)*32 + c32] =
            *(const uint4*)&As[pix*272 + ch];
    }
}

// ---------------------------------------------------------------------------
// Kernel QP: fused query projection.
// ---------------------------------------------------------------------------
__global__ __launch_bounds__(512, 4) void qp_kernel(const float* __restrict__ query,
                                                    const unsigned short* __restrict__ Wchf,
                                                    const unsigned short* __restrict__ Wclf,
                                                    const float* __restrict__ b_off,
                                                    const float* __restrict__ b_attn,
                                                    const float* __restrict__ reff,
                                                    float* __restrict__ locs,
                                                    float* __restrict__ aw) {
    __shared__ __align__(16) unsigned short Ah[32 * 256];   // 16 KB
    __shared__ __align__(16) unsigned short Al[32 * 256];   // 16 KB
    int t = threadIdx.x;
    int row0 = blockIdx.x * 32;
    int ty = blockIdx.y;
    {
        int row = t & 31;
        int c2 = t >> 5;
        const float* src = query + (size_t)(row0 + row) * 256;
#pragma unroll
        for (int cc = 0; cc < 2; ++cc) {
            int c = c2 * 2 + cc;
            float4 v0 = *(const float4*)&src[c*8 + 0];
            float4 v1 = *(const float4*)&src[c*8 + 4];
            float f[8] = {v0.x, v0.y, v0.z, v0.w, v1.x, v1.y, v1.z, v1.w};
            unsigned short h[8], l[8];
#pragma unroll
            for (int j = 0; j < 8; ++j) {
                h[j] = f2bf(f[j]);
                l[j] = f2bf(f[j] - bf2f(h[j]));
            }
            uint4 ph, pl;
            ph.x = h[0] | ((unsigned)h[1] << 16); ph.y = h[2] | ((unsigned)h[3] << 16);
            ph.z = h[4] | ((unsigned)h[5] << 16); ph.w = h[6] | ((unsigned)h[7] << 16);
            pl.x = l[0] | ((unsigned)l[1] << 16); pl.y = l[2] | ((unsigned)l[3] << 16);
            pl.z = l[4] | ((unsigned)l[5] << 16); pl.w = l[6] | ((unsigned)l[7] << 16);
            int pos = row * 256 + ((c ^ row) << 3);
            *(uint4*)&Ah[pos] = ph;
            *(uint4*)&Al[pos] = pl;
        }
    }
    __syncthreads();
    int wave = t >> 6, lane = t & 63, quad = lane >> 4, l15 = lane & 15;
    int ms = wave & 1;
    int ng = wave >> 1;
    int arow = ms*16 + l15;
    int bq = row0 >> 12;
    int tile0 = ty*12 + ng*3;
    f32x4 acc[3];
#pragma unroll
    for (int i = 0; i < 3; ++i) acc[i] = (f32x4){0.f, 0.f, 0.f, 0.f};

#define QP_FB(i, kk) (((size_t)((tile0 + (i))*8 + (kk)) << 9) + lane*8)

    if (ty < 2) {
        short8 bhA[3], blA[3], bhB[3], blB[3];
#pragma unroll
        for (int i = 0; i < 3; ++i) {
            bhA[i] = *(const short8*)&Wchf[QP_FB(i, 0)];
            blA[i] = *(const short8*)&Wclf[QP_FB(i, 0)];
        }
#pragma unroll
        for (int kk = 0; kk < 8; kk += 2) {
            if (kk + 1 < 8) {
#pragma unroll
                for (int i = 0; i < 3; ++i) {
                    bhB[i] = *(const short8*)&Wchf[QP_FB(i, kk+1)];
                    blB[i] = *(const short8*)&Wclf[QP_FB(i, kk+1)];
                }
            }
            {
                int apos = arow*256 + (((kk*4+quad) ^ arow) << 3);
                short8 a_h = *(const short8*)&Ah[apos];
                short8 a_l = *(const short8*)&Al[apos];
#pragma unroll
                for (int i = 0; i < 3; ++i) {
                    acc[i] = __builtin_amdgcn_mfma_f32_16x16x32_bf16(a_h, bhA[i], acc[i], 0, 0, 0);
                    acc[i] = __builtin_amdgcn_mfma_f32_16x16x32_bf16(a_l, bhA[i], acc[i], 0, 0, 0);
                    acc[i] = __builtin_amdgcn_mfma_f32_16x16x32_bf16(a_h, blA[i], acc[i], 0, 0, 0);
                }
            }
            if (kk + 2 < 8) {
#pragma unroll
                for (int i = 0; i < 3; ++i) {
                    bhA[i] = *(const short8*)&Wchf[QP_FB(i, kk+2)];
                    blA[i] = *(const short8*)&Wclf[QP_FB(i, kk+2)];
                }
            }
            if (kk + 1 < 8) {
                int k1 = kk + 1;
                int apos = arow*256 + (((k1*4+quad) ^ arow) << 3);
                short8 a_h = *(const short8*)&Ah[apos];
                short8 a_l = *(const short8*)&Al[apos];
#pragma unroll
                for (int i = 0; i < 3; ++i) {
                    acc[i] = __builtin_amdgcn_mfma_f32_16x16x32_bf16(a_h, bhB[i], acc[i], 0, 0, 0);
                    acc[i] = __builtin_amdgcn_mfma_f32_16x16x32_bf16(a_l, bhB[i], acc[i], 0, 0, 0);
                    acc[i] = __builtin_amdgcn_mfma_f32_16x16x32_bf16(a_h, blB[i], acc[i], 0, 0, 0);
                }
            }
        }
#pragma unroll
        for (int i = 0; i < 3; ++i) {
            int j = (tile0 + i)*16 + l15;
            int n_cam = j >> 6;
            int xy = j & 1;
            float bias = b_off[j];
#pragma unroll
            for (int r = 0; r < 4; ++r) {
                int q = row0 + ms*16 + quad*4 + r;
                int qq = q & (Qq-1);
                float refv = reff[((bq*Nn + n_cam)*Qq + qq)*3 + xy];
                locs[(size_t)q*384 + j] = refv + tanhf(acc[i][r] + bias) * 0.5f;
            }
        }
    } else {
        short8 bhA[3], bhB[3];
#pragma unroll
        for (int i = 0; i < 3; ++i) bhA[i] = *(const short8*)&Wchf[QP_FB(i, 0)];
#pragma unroll
        for (int kk = 0; kk < 8; kk += 2) {
            if (kk + 1 < 8) {
#pragma unroll
                for (int i = 0; i < 3; ++i) bhB[i] = *(const short8*)&Wchf[QP_FB(i, kk+1)];
            }
            {
                int apos = arow*256 + (((kk*4+quad) ^ arow) << 3);
                short8 a_h = *(const short8*)&Ah[apos];
#pragma unroll
                for (int i = 0; i < 3; ++i)
                    acc[i] = __builtin_amdgcn_mfma_f32_16x16x32_bf16(a_h, bhA[i], acc[i], 0, 0, 0);
            }
            if (kk + 2 < 8) {
#pragma unroll
                for (int i = 0; i < 3; ++i) bhA[i] = *(const short8*)&Wchf[QP_FB(i, kk+2)];
            }
            if (kk + 1 < 8) {
                int k1 = kk + 1;
                int apos = arow*256 + (((k1*4+quad) ^ arow) << 3);
                short8 a_h = *(const short8*)&Ah[apos];
#pragma unroll
                for (int i = 0; i < 3; ++i)
                    acc[i] = __builtin_amdgcn_mfma_f32_16x16x32_bf16(a_h, bhB[i], acc[i], 0, 0, 0);
            }
        }
#pragma unroll
        for (int i = 0; i < 3; ++i) {
            int j2 = (tile0 + i)*16 + l15 - 384;
            int n_cam = j2 >> 5;
            float bias = b_attn[j2];
#pragma unroll
            for (int r = 0; r < 4; ++r) {
                int q = row0 + ms*16 + quad*4 + r;
                int qq = q & (Qq-1);
                float fov = reff[((bq*Nn + n_cam)*Qq + qq)*3 + 2];
                float lg = (acc[i][r] + bias) * fov;
                float mx = fmaxf(lg, __shfl_xor(lg, 1));
                mx = fmaxf(mx, __shfl_xor(mx, 2));
                float e = expf(lg - mx);
                float s = e + __shfl_xor(e, 1);
                s = s + __shfl_xor(s, 2);
                aw[(size_t)q*192 + j2] = e / s;
            }
        }
    }
#undef QP_FB
}

// ---------------------------------------------------------------------------
// Kernel S: bilinear sampling + weighted sum -> wsum (bf16).
// 512 thr = 8 waves = 8 co-binned queries; XCD-chunk interleave.
// LDS diet: weights float2 per corner-pair (25 KB) + PIXEL-INDEX ushort2
// offsets (12.5 KB) -> 37.6 KB -> 4 blocks/CU (was 3).
// ---------------------------------------------------------------------------
__global__ __launch_bounds__(512, 4) void samp_kernel(const unsigned short* __restrict__ val,
                                                      const float* __restrict__ locs,
                                                      const float* __restrict__ aw,
                                                      const int* __restrict__ perm,
                                                      unsigned short* __restrict__ wsum) {
    __shared__ __align__(16) float2  swgtp[8][2][196];
    __shared__ __align__(8)  ushort2 soffp[8][2][196];
    int t = threadIdx.x, wv = t >> 6, lane = t & 63;
    int bi = blockIdx.x;
    int q = perm[(bi & 7) * 1024 + (bi >> 3) * 8 + wv];
    int b = q >> 12;
#pragma unroll
    for (int j = 0; j < 3; ++j) {
        int s = lane + 64*j;
        float2 xy = *(const float2*)&locs[(size_t)q*384 + 2*s];
        float w = aw[(size_t)q*192 + s];
        float gx = (xy.x + 1.0f)*48.0f - 0.5f;
        float gy = (xy.y + 1.0f)*32.0f - 0.5f;
        float x0f = floorf(gx), y0f = floorf(gy);
        float wx = gx - x0f, wy = gy - y0f;
        int ix = (int)x0f, iy = (int)y0f;
        bool vx0 = (unsigned)ix       < (unsigned)Ww;
        bool vx1 = (unsigned)(ix + 1) < (unsigned)Ww;
        bool vy0 = (unsigned)iy       < (unsigned)Hh;
        bool vy1 = (unsigned)(iy + 1) < (unsigned)Hh;
        int ix0 = min(max(ix, 0), Ww-1), ix1 = min(max(ix+1, 0), Ww-1);
        int iy0 = min(max(iy, 0), Hh-1), iy1 = min(max(iy+1, 0), Hh-1);
        float2 w0p, w1p;
        w0p.x = (vx0 && vy0) ? w*(1.0f-wx)*(1.0f-wy) : 0.0f;
        w0p.y = (vx1 && vy0) ? w*wx*(1.0f-wy)        : 0.0f;
        w1p.x = (vx0 && vy1) ? w*(1.0f-wx)*wy        : 0.0f;
        w1p.y = (vx1 && vy1) ? w*wx*wy               : 0.0f;
        swgtp[wv][0][s] = w0p;
        swgtp[wv][1][s] = w1p;
        ushort2 o0p, o1p;
        o0p.x = (unsigned short)(iy0*Ww + ix0);
        o0p.y = (unsigned short)(iy0*Ww + ix1);
        o1p.x = (unsigned short)(iy1*Ww + ix0);
        o1p.y = (unsigned short)(iy1*Ww + ix1);
        soffp[wv][0][s] = o0p;
        soffp[wv][1][s] = o1p;
    }
    __syncthreads();
    int cg   = lane >> 5;
    int head = (lane >> 2) & 7;
    int oc   = lane & 3;
    const char* vbase = (const char*)val + (size_t)(b*Nn*HEADS + head)*HW*64 + oc*16;
    float a[8] = {0.f,0.f,0.f,0.f,0.f,0.f,0.f,0.f};
#pragma unroll
    for (int n = 0; n < Nn; ++n) {
        const char* vb = vbase + (size_t)n*HEADS*HW*64;
#pragma unroll
        for (int p = 0; p < POINTS; ++p) {
            int s = (n*HEADS + head)*POINTS + p;
            float2 wp = swgtp[wv][cg][s];
            ushort2 op = soffp[wv][cg][s];
            uint4 u0 = *(const uint4*)(vb + (int)op.x * 64);
            uint4 u1 = *(const uint4*)(vb + (int)op.y * 64);
            float w0 = wp.x, w1 = wp.y;
            a[0] += w0*bflo(u0.x); a[1] += w0*bfhi(u0.x);
            a[2] += w0*bflo(u0.y); a[3] += w0*bfhi(u0.y);
            a[4] += w0*bflo(u0.z); a[5] += w0*bfhi(u0.z);
            a[6] += w0*bflo(u0.w); a[7] += w0*bfhi(u0.w);
            a[0] += w1*bflo(u1.x); a[1] += w1*bfhi(u1.x);
            a[2] += w1*bflo(u1.y); a[3] += w1*bfhi(u1.y);
            a[4] += w1*bflo(u1.z); a[5] += w1*bfhi(u1.z);
            a[6] += w1*bflo(u1.w); a[7] += w1*bfhi(u1.w);
        }
    }
#pragma unroll
    for (int j = 0; j < 8; ++j) a[j] += __shfl_xor(a[j], 32);
    if (cg == 0) {
        int c = head*32 + oc*8;
        uint4 o;
        o.x = packbf(a[0], a[1]);
        o.y = packbf(a[2], a[3]);
        o.z = packbf(a[4], a[5]);
        o.w = packbf(a[6], a[7]);
        *(uint4*)&wsum[(size_t)q*256 + c] = o;
    }
}

// ---------------------------------------------------------------------------
// Kernel O (MFMA): out = wsum(bf16) @ W_out + b_out. Frag-linear Wotf.
// ---------------------------------------------------------------------------
__global__ __launch_bounds__(256) void out_mfma_kernel(const unsigned short* __restrict__ wsum,
                                                       const unsigned short* __restrict__ Wotf,
                                                       const float* __restrict__ b_out,
                                                       float* __restrict__ out) {
    int t = threadIdx.x;
    int row0 = blockIdx.x * 64;
    int col0 = blockIdx.y * 128;
    int wave = t >> 6, lane = t & 63, quad = lane >> 4, l15 = lane & 15;
    int wm = wave & 1;
    int wn = wave >> 1;
    f32x4 acc[2][4];
#pragma unroll
    for (int i = 0; i < 2; ++i)
#pragma unroll
        for (int j = 0; j < 4; ++j) acc[i][j] = (f32x4){0.f, 0.f, 0.f, 0.f};
#pragma unroll
    for (int kk = 0; kk < 8; ++kk) {
        short8 a[2];
#pragma unroll
        for (int mt = 0; mt < 2; ++mt)
            a[mt] = *(const short8*)&wsum[(size_t)(row0 + wm*32 + mt*16 + l15)*256 + kk*32 + quad*8];
#pragma unroll
        for (int nt = 0; nt < 4; ++nt) {
            size_t fb = ((size_t)((blockIdx.y*8 + wn*4 + nt)*8 + kk) << 9) + lane*8;
            short8 bfr = *(const short8*)&Wotf[fb];
            acc[0][nt] = __builtin_amdgcn_mfma_f32_16x16x32_bf16(a[0], bfr, acc[0][nt], 0, 0, 0);
            acc[1][nt] = __builtin_amdgcn_mfma_f32_16x16x32_bf16(a[1], bfr, acc[1][nt], 0, 0, 0);
        }
    }
#pragma unroll
    for (int nt = 0; nt < 4; ++nt) {
        int col = col0 + wn*64 + nt*16 + l15;
        float bias = b_out[col];
#pragma unroll
        for (int mt = 0; mt < 2; ++mt) {
#pragma unroll
            for (int r = 0; r < 4; ++r) {
                int q = row0 + wm*32 + mt*16 + quad*4 + r;
                out[(size_t)q*256 + col] = acc[mt][nt][r] + bias;
            }
        }
    }
}

extern "C" void kernel_launch(void* const* d_in, const int* in_sizes, int n_in,
                              void* d_out, int out_size, void* d_ws, size_t ws_size,
                              hipStream_t stream) {
    const float* query  = (const float*)d_in[0];
    const float* qc     = (const float*)d_in[1];
    const float* feats  = (const float*)d_in[2];
    const float* intr   = (const float*)d_in[3];
    const float* invE   = (const float*)d_in[4];
    const float* W_off  = (const float*)d_in[5];
    const float* b_off  = (const float*)d_in[6];
    const float* W_attn = (const float*)d_in[7];
    const float* b_attn = (const float*)d_in[8];
    const float* W_val  = (const float*)d_in[9];
    const float* b_val  = (const float*)d_in[10];
    const float* W_out  = (const float*)d_in[11];
    const float* b_out  = (const float*)d_in[12];
    float* out = (float*)d_out;
    float* ws  = (float*)d_ws;
    unsigned short* val  = (unsigned short*)(ws + WS_VAL);
    unsigned short* Wtf  = (unsigned short*)(ws + WS_WTF);
    unsigned short* Wchf = (unsigned short*)(ws + WS_WCHF);
    unsigned short* Wclf = (unsigned short*)(ws + WS_WCLF);
    unsigned short* Wotf = (unsigned short*)(ws + WS_WOTF);
    float* locs = ws + WS_LOCS;
    float* aw   = ws + WS_AW;
    float* reff = ws + WS_REFF;
    unsigned short* wsum = (unsigned short*)(ws + WS_WSUM);
    int* hist = (int*)(ws + WS_HIST);
    int* boff = (int*)(ws + WS_BOFF);
    int* bin  = (int*)(ws + WS_BIN);
    int* perm = (int*)(ws + WS_PERM);

    hipMemsetAsync(hist, 0, 4096*sizeof(int), stream);
    hipLaunchKernelGGL(prep_kernel, dim3(1120), dim3(256), 0, stream,
                       qc, intr, invE, reff, W_val, W_off, W_attn, W_out,
                       Wtf, Wchf, Wclf, Wotf, hist, bin);
    hipLaunchKernelGGL(scan_kernel, dim3(1), dim3(256), 0, stream,
                       hist, boff);
    hipLaunchKernelGGL(scatter_kernel, dim3(BQ/256), dim3(256), 0, stream,
                       bin, boff, perm);
    hipLaunchKernelGGL(vp_mfma_kernel, dim3(HW/64, Bb*Nn), dim3(512), 0, stream,
                       feats, Wtf, b_val, val);
    hipLaunchKernelGGL(qp_kernel, dim3(BQ/32, 3), dim3(512), 0, stream,
                       query, Wchf, Wclf, b_off, b_attn, reff, locs, aw);
    hipLaunchKernelGGL(samp_kernel, dim3(BQ/8), dim3(512), 0, stream,
                       val, locs, aw, perm, wsum);
    hipLaunchKernelGGL(out_mfma_kernel, dim3(BQ/64, 2), dim3(256), 0, stream,
                       wsum, Wotf, b_out, out);
}